// Round 2
// baseline (598.129 us; speedup 1.0000x reference)
//
#include <hip/hip_runtime.h>
#include <math.h>

#define Bb 128
#define Tt 1024
#define Ll 96

typedef float v2f __attribute__((ext_vector_type(2)));
typedef float v4f __attribute__((ext_vector_type(4)));

// One block = one batch = ONE wave (64 lanes). Lane i owns states m=2i,2i+1
// (i<48; lanes 48-63 duplicate lane 47 on clamped addresses, harmless).
//
// Linear-space recurrence (log/exp off the serial critical path):
//   q_t = (E^T q_{t-1}) * exp(x_t) * 2^{-k_{t-1}},  E = exp(trans)
//   k_t = floor(log2 q_t[0]) via exponent bits (readfirstlane -> SALU)
//   true state_t = log q_t + D_t,  D_t += k_{t-1}*ln2  (Dk integer: EXACT)
//
// E lives in 96 NAMED v2f registers (192 VGPRs) — no arrays, no runtime
// indexing, so the allocator cannot demote it to scratch (rounds 0/1 both
// silently spilled array-based E: VGPR_Count 68/116 < array size).
// No per-step barrier and no manual s_waitcnt: same-wave DS ops execute in
// order in the LDS pipe; compiler inserts lgkmcnt before uses.
__global__ __launch_bounds__(64, 1) void crf_fwd_kernel(
    const float* __restrict__ inputs,      // (B, T, L) fp32
    const int*   __restrict__ labels_idx,  // (B, T) int32
    const float* __restrict__ trans,       // (L, L) fp32
    float*       __restrict__ out)         // (B, 1) fp32
{
    const int b   = blockIdx.x;
    const int i   = threadIdx.x;                     // 0..63
    const int col = (2 * i < Ll) ? 2 * i : (Ll - 2); // clamp lanes 48..63

    __shared__ __align__(16) float pbuf[2][Ll];      // double-buffered q

    const float* xbase = inputs + (size_t)b * Tt * Ll;

    // ---- point_score + trans_score first (keeps E live-range short) ----
    float ps = 0.f;
    {
        const int* lb = labels_idx + b * Tt;
        #pragma unroll 4
        for (int t = i; t < Tt; t += 64) {
            int i0 = lb[t];
            ps += xbase[t * Ll + i0];
            if (t < Tt - 1) ps += trans[i0 * Ll + lb[t + 1]];
        }
        #pragma unroll
        for (int off = 32; off; off >>= 1) ps += __shfl_xor(ps, off, 64);
    }

    // ---- E in 96 named v2f registers ----
    // EA<p> = {E[2p][col],   E[2p+1][col]}   (output m = col)
    // EB<p> = {E[2p][col+1], E[2p+1][col+1]} (output m = col+1)
    v2f EA0,EA1,EA2,EA3,EA4,EA5,EA6,EA7,EA8,EA9,EA10,EA11,EA12,EA13,EA14,EA15,
        EA16,EA17,EA18,EA19,EA20,EA21,EA22,EA23,EA24,EA25,EA26,EA27,EA28,EA29,
        EA30,EA31,EA32,EA33,EA34,EA35,EA36,EA37,EA38,EA39,EA40,EA41,EA42,EA43,
        EA44,EA45,EA46,EA47;
    v2f EB0,EB1,EB2,EB3,EB4,EB5,EB6,EB7,EB8,EB9,EB10,EB11,EB12,EB13,EB14,EB15,
        EB16,EB17,EB18,EB19,EB20,EB21,EB22,EB23,EB24,EB25,EB26,EB27,EB28,EB29,
        EB30,EB31,EB32,EB33,EB34,EB35,EB36,EB37,EB38,EB39,EB40,EB41,EB42,EB43,
        EB44,EB45,EB46,EB47;

#define EINIT(p) { \
        v2f r0 = *reinterpret_cast<const v2f*>(&trans[(2 * (p))     * Ll + col]); \
        v2f r1 = *reinterpret_cast<const v2f*>(&trans[(2 * (p) + 1) * Ll + col]); \
        EA##p = (v2f){__expf(r0.x), __expf(r1.x)}; \
        EB##p = (v2f){__expf(r0.y), __expf(r1.y)}; }
    EINIT(0)  EINIT(1)  EINIT(2)  EINIT(3)  EINIT(4)  EINIT(5)  EINIT(6)  EINIT(7)
    EINIT(8)  EINIT(9)  EINIT(10) EINIT(11) EINIT(12) EINIT(13) EINIT(14) EINIT(15)
    EINIT(16) EINIT(17) EINIT(18) EINIT(19) EINIT(20) EINIT(21) EINIT(22) EINIT(23)
    EINIT(24) EINIT(25) EINIT(26) EINIT(27) EINIT(28) EINIT(29) EINIT(30) EINIT(31)
    EINIT(32) EINIT(33) EINIT(34) EINIT(35) EINIT(36) EINIT(37) EINIT(38) EINIT(39)
    EINIT(40) EINIT(41) EINIT(42) EINIT(43) EINIT(44) EINIT(45) EINIT(46) EINIT(47)
#undef EINIT

    // ---- q_0 = exp(x_0); seed normalizer from its exponent field ----
    v2f x0 = *reinterpret_cast<const v2f*>(&xbase[col]);
    v2f qv = (v2f){__expf(x0.x), __expf(x0.y)};
    if (i < 48) *reinterpret_cast<v2f*>(&pbuf[0][2 * i]) = qv;
    unsigned gb = (unsigned)__builtin_amdgcn_readfirstlane((int)__float_as_uint(qv.x));
    int   kcur = (int)((gb >> 23) & 0xffu) - 127;               // floor(log2 q[0])
    float r    = __uint_as_float((unsigned)(127 - kcur) << 23); // exact 2^-k
    int   Dk   = 0;

    // ---- x prefetch (depth 2) + exp(x) pipelined one step ahead ----
    v2f xr1 = *reinterpret_cast<const v2f*>(&xbase[1 * Ll + col]);
    v2f exw = (v2f){__expf(xr1.x), __expf(xr1.y)};  // exp(x_1)
    v2f xa  = *reinterpret_cast<const v2f*>(&xbase[2 * Ll + col]);
    v2f xb  = *reinterpret_cast<const v2f*>(&xbase[3 * Ll + col]);

    for (int t = 1; t < Tt; ++t) {
        const int wp = t & 1, rp = wp ^ 1;

        Dk += kcur;              // D_t += k_{t-1} (integer, exact)
        v2f w = exw * r;         // exp(x_t) * 2^-k : off the FMA critical path

        // ---- matvec: 24 broadcast b128 reads, 96 pk-FMAs, all reg operands ----
        const v4f* qb = reinterpret_cast<const v4f*>(&pbuf[rp][0]);
        v2f a00 = {0.f, 0.f}, a01 = {0.f, 0.f}, a10 = {0.f, 0.f}, a11 = {0.f, 0.f};
#define FSTEP(J, P0, P1, P2, P3) { \
        v4f qA = qb[2 * (J)]; \
        v4f qB = qb[2 * (J) + 1]; \
        v2f qAlo = {qA.x, qA.y}, qAhi = {qA.z, qA.w}; \
        v2f qBlo = {qB.x, qB.y}, qBhi = {qB.z, qB.w}; \
        a00 += qAlo * EA##P0;  a10 += qAlo * EB##P0; \
        a01 += qAhi * EA##P1;  a11 += qAhi * EB##P1; \
        a00 += qBlo * EA##P2;  a10 += qBlo * EB##P2; \
        a01 += qBhi * EA##P3;  a11 += qBhi * EB##P3; }
        FSTEP(0,  0,  1,  2,  3)
        FSTEP(1,  4,  5,  6,  7)
        FSTEP(2,  8,  9,  10, 11)
        FSTEP(3,  12, 13, 14, 15)
        FSTEP(4,  16, 17, 18, 19)
        FSTEP(5,  20, 21, 22, 23)
        FSTEP(6,  24, 25, 26, 27)
        FSTEP(7,  28, 29, 30, 31)
        FSTEP(8,  32, 33, 34, 35)
        FSTEP(9,  36, 37, 38, 39)
        FSTEP(10, 40, 41, 42, 43)
        FSTEP(11, 44, 45, 46, 47)
#undef FSTEP
        v2f sA = a00 + a01;
        v2f sB = a10 + a11;
        qv = (v2f){sA.x + sA.y, sB.x + sB.y} * w;

        if (i < 48) *reinterpret_cast<v2f*>(&pbuf[wp][2 * i]) = qv;
        // same-wave DS ops are in-order in the LDS pipe: no barrier, no manual
        // waitcnt; the compiler inserts lgkmcnt before next iteration's uses.

        // ---- off-path bookkeeping for step t+1 (SALU + 2 transcendentals) ----
        gb   = (unsigned)__builtin_amdgcn_readfirstlane((int)__float_as_uint(qv.x));
        kcur = (int)((gb >> 23) & 0xffu) - 127;
        r    = __uint_as_float((unsigned)(127 - kcur) << 23);

        exw = (v2f){__expf(xa.x), __expf(xa.y)};    // exp(x_{t+1})
        xa  = xb;
        int row = t + 3; if (row > Tt - 1) row = Tt - 1;
        xb  = *reinterpret_cast<const v2f*>(&xbase[row * Ll + col]);
    }

    // ---- log_norm = Dk*ln2 + log(sum_m q_T[m]); out = log_norm - scores ----
    float s = (i < 48) ? (qv.x + qv.y) : 0.f;
    #pragma unroll
    for (int off = 32; off; off >>= 1) s += __shfl_xor(s, off, 64);
    if (i == 0) {
        double ln = (double)Dk * 0.6931471805599453 + log((double)s);
        out[b] = (float)(ln - (double)ps);
    }
}

extern "C" void kernel_launch(void* const* d_in, const int* in_sizes, int n_in,
                              void* d_out, int out_size, void* d_ws, size_t ws_size,
                              hipStream_t stream) {
    const float* inputs     = (const float*)d_in[0];
    const int*   labels_idx = (const int*)d_in[1];
    const float* trans      = (const float*)d_in[2];
    float*       out        = (float*)d_out;

    crf_fwd_kernel<<<dim3(Bb), dim3(64), 0, stream>>>(inputs, labels_idx, trans, out);
}